// Round 2
// baseline (204.073 us; speedup 1.0000x reference)
//
#include <hip/hip_runtime.h>

// LateralEI: out = GAIN * rownorm(K) @ h, K = 0.8*exp(-d2/0.72) - exp(-d2/2.88)
// d2 = ||z_i - z_j||^2, z: [8192][2] f32, h: [8192][128] f32, out: [8192][128] f32
//
// Structure: flash-style fused kernel. Per block: 32 rows, K-loop over j in
// tiles of 64. All 512 threads produce w-values directly into the MFMA
// A-fragment packed LDS layout (A[m=lane&15][k=quad*8+j], verified m120);
// B-fragments are direct global dwordx4 loads from a bf16 pre-transposed
// copy of h (hT in d_ws), layout B[k=quad*8+j][n=lane&15] (dual of A).
// Rowsum accumulated in fp32 registers, reduced in LDS at the end.

typedef float f32x4 __attribute__((ext_vector_type(4)));
typedef short s16x8 __attribute__((ext_vector_type(8)));

#define NPTS 8192
#define DH 128
#define BM 32
#define BK 64
#define NT (NPTS / BK)  // 128 K-tiles

// -log2(e)/(2*sigma^2):
#define A_E (-2.0037431123f)  // sigma_e = 0.6
#define A_I (-0.5009357781f)  // sigma_i = 1.2
#define GAIN_C 0.05f

// ---------- pre-pass: h [8192][128] f32  ->  hT [128][8192] bf16 (d_ws) ----------
__global__ __launch_bounds__(256) void h_transpose_bf16(
    const float* __restrict__ h, unsigned short* __restrict__ hT) {
  // row stride 72 ushorts = 144 B (16B-aligned rows, odd 16B-chunk count kills
  // read-side conflicts; write side is b16, cheap for a one-shot 4MB pass)
  __shared__ __align__(16) unsigned short tile[DH * 72];
  const int t = threadIdx.x;
  const int j0 = blockIdx.x * 64;
  const int n = t & 127;
  const int g = t >> 7;  // 0..1
#pragma unroll 4
  for (int p = 0; p < 32; ++p) {
    const int jj = g * 32 + p;
    const float v = h[(j0 + jj) * DH + n];  // coalesced: lanes sweep n
    unsigned int u = __float_as_uint(v);
    u = (u + 0x7fffu + ((u >> 16) & 1u)) >> 16;  // RNE to bf16
    tile[n * 72 + jj] = (unsigned short)u;
  }
  __syncthreads();
  // write-out: 128 rows x 8 chunks of 8 bf16 = 1024 chunk-writes, 256 threads
  // -> 4 iterations. (R1 bug: k<2 with rn=u>>2,c=u&3 only wrote chunks 0-3,
  //  leaving hT cols 32..63 of every 64-block poisoned -> 1/sqrt(2) absmax.)
#pragma unroll
  for (int k = 0; k < 4; ++k) {
    const int u = t + k * 256;
    const int rn = u >> 3;  // 0..127
    const int c = u & 7;    // 16B chunk within the 64-element row
    const s16x8 val = *(const s16x8*)&tile[rn * 72 + c * 8];
    *(s16x8*)(hT + rn * NPTS + j0 + c * 8) = val;  // 64B segments per 4 lanes
  }
}

// ---------- main fused kernel ----------
__global__ __launch_bounds__(512) void lateral_ei_main(
    const float* __restrict__ z, const unsigned short* __restrict__ hT,
    float* __restrict__ out) {
  // w packed in A-frag order: [buf][slot(rg,ks,lane)][8 bf16] = 2 x 4KB
  __shared__ __align__(16) unsigned int s_wp[2][1024];
  __shared__ float s_rsp[512];
  __shared__ float s_rsum[BM];

  const int t = threadIdx.x;
  const int i0 = blockIdx.x * BM;

  // ---- producer mapping: thread -> (slot, half) -> (row m, 4 consecutive k)
  const int s = t >> 1;
  const int half = t & 1;
  const int p_l = s & 63;
  const int p_ks = (s >> 6) & 1;
  const int p_rg = s >> 7;
  const int p_m = p_rg * 16 + (p_l & 15);
  const int p_k0 = p_ks * 32 + ((p_l >> 4) & 3) * 8 + half * 4;
  const float zix = z[(i0 + p_m) * 2 + 0];
  const float ziy = z[(i0 + p_m) * 2 + 1];
  const float* zjp = z + p_k0 * 2;  // + j0*2 per tile

  // ---- consumer mapping: wave -> (row-group, col-group), lane -> (quad, nf)
  const int lane = t & 63;
  const int wv = t >> 6;
  const int c_rg = wv & 1;   // rows c_rg*16 .. +16
  const int c_cg = wv >> 1;  // cols c_cg*32 .. +32 (2 fragments)
  const int q = lane >> 4;
  const int nf = lane & 15;
  const unsigned short* hb0 = hT + (c_cg * 32 + nf) * NPTS + q * 8;
  const unsigned short* hb1 = hb0 + 16 * NPTS;

  f32x4 acc0 = {0.f, 0.f, 0.f, 0.f};
  f32x4 acc1 = {0.f, 0.f, 0.f, 0.f};
  float rs = 0.f;

  for (int tl = 0; tl < NT; ++tl) {
    const int buf = tl & 1;
    const int j0 = tl * BK;

    // prefetch B fragments for this tile (global dwordx4, L1-resident re-reads)
    const s16x8 b00 = *(const s16x8*)(hb0 + j0);
    const s16x8 b01 = *(const s16x8*)(hb0 + j0 + 32);
    const s16x8 b10 = *(const s16x8*)(hb1 + j0);
    const s16x8 b11 = *(const s16x8*)(hb1 + j0 + 32);

    // ---- produce 4 w values (the VALU-bound core: 8 subs/fmas + 8 v_exp)
    const f32x4 pa = *(const f32x4*)(zjp + j0 * 2);      // (x,y) of j+0, j+1
    const f32x4 pb = *(const f32x4*)(zjp + j0 * 2 + 4);  // (x,y) of j+2, j+3
    const float dx0 = zix - pa[0], dy0 = ziy - pa[1];
    const float dx1 = zix - pa[2], dy1 = ziy - pa[3];
    const float dx2 = zix - pb[0], dy2 = ziy - pb[1];
    const float dx3 = zix - pb[2], dy3 = ziy - pb[3];
    const float d0 = dx0 * dx0 + dy0 * dy0;
    const float d1 = dx1 * dx1 + dy1 * dy1;
    const float d2 = dx2 * dx2 + dy2 * dy2;
    const float d3 = dx3 * dx3 + dy3 * dy3;
    const float w0 = 0.8f * __builtin_amdgcn_exp2f(d0 * A_E) - __builtin_amdgcn_exp2f(d0 * A_I);
    const float w1 = 0.8f * __builtin_amdgcn_exp2f(d1 * A_E) - __builtin_amdgcn_exp2f(d1 * A_I);
    const float w2 = 0.8f * __builtin_amdgcn_exp2f(d2 * A_E) - __builtin_amdgcn_exp2f(d2 * A_I);
    const float w3 = 0.8f * __builtin_amdgcn_exp2f(d3 * A_E) - __builtin_amdgcn_exp2f(d3 * A_I);
    rs += (w0 + w1) + (w2 + w3);  // fp32 rowsum (pre-bf16-rounding; error ~1e-7)

    // truncate-to-bf16 pack (3 int ops/pair); write b64, conflict-free
    const unsigned int u01 =
        (__float_as_uint(w0) >> 16) | (__float_as_uint(w1) & 0xffff0000u);
    const unsigned int u23 =
        (__float_as_uint(w2) >> 16) | (__float_as_uint(w3) & 0xffff0000u);
    unsigned int* wp = &s_wp[buf][t * 2];  // == slot*4 + half*2
    wp[0] = u01;
    wp[1] = u23;

    __syncthreads();  // single barrier per tile (w-pack double-buffered)

    // ---- consume: 2 K-steps x 2 column fragments
    const unsigned int* ab = &s_wp[buf][c_rg * 512 + lane * 4];
    const s16x8 a0 = *(const s16x8*)ab;          // ks=0
    const s16x8 a1 = *(const s16x8*)(ab + 256);  // ks=1
    acc0 = __builtin_amdgcn_mfma_f32_16x16x32_bf16(a0, b00, acc0, 0, 0, 0);
    acc1 = __builtin_amdgcn_mfma_f32_16x16x32_bf16(a0, b10, acc1, 0, 0, 0);
    acc0 = __builtin_amdgcn_mfma_f32_16x16x32_bf16(a1, b01, acc0, 0, 0, 0);
    acc1 = __builtin_amdgcn_mfma_f32_16x16x32_bf16(a1, b11, acc1, 0, 0, 0);
  }

  // ---- rowsum reduction: 16 partials per row
  s_rsp[t] = rs;
  __syncthreads();
  if (t < BM) {
    const int rg = t >> 4;
    const int mf = t & 15;
    float sum = 0.f;
#pragma unroll
    for (int ks = 0; ks < 2; ++ks)
#pragma unroll
      for (int qq = 0; qq < 4; ++qq)
#pragma unroll
        for (int hh = 0; hh < 2; ++hh)
          sum += s_rsp[((rg * 128 + ks * 64 + qq * 16 + mf) << 1) | hh];
    s_rsum[t] = sum;
  }
  __syncthreads();

  // ---- epilogue: C/D layout col=lane&15, row=quad*4+reg (verified m89/m91)
#pragma unroll
  for (int r = 0; r < 4; ++r) {
    const int m = c_rg * 16 + q * 4 + r;
    const float sc = GAIN_C / (s_rsum[m] + 1e-6f);
    const int o = (i0 + m) * DH + c_cg * 32 + nf;
    out[o] = acc0[r] * sc;
    out[o + 16] = acc1[r] * sc;
  }
}

extern "C" void kernel_launch(void* const* d_in, const int* in_sizes, int n_in,
                              void* d_out, int out_size, void* d_ws, size_t ws_size,
                              hipStream_t stream) {
  (void)in_sizes; (void)n_in; (void)out_size; (void)ws_size;
  const float* z = (const float*)d_in[0];
  const float* h = (const float*)d_in[1];
  float* out = (float*)d_out;
  unsigned short* hT = (unsigned short*)d_ws;  // 128*8192 bf16 = 2 MiB scratch

  h_transpose_bf16<<<NPTS / 64, 256, 0, stream>>>(h, hT);
  lateral_ei_main<<<NPTS / BM, 512, 0, stream>>>(z, hT, out);
}

// Round 3
// 188.787 us; speedup vs baseline: 1.0810x; 1.0810x over previous
//
#include <hip/hip_runtime.h>

// LateralEI: out = GAIN * rownorm(K) @ h, K = 0.8*exp(-d2/0.72) - exp(-d2/2.88)
// z: [8192][2] f32, h: [8192][128] f32, out: [8192][128] f32
//
// R3 structure: barrier-free main loop. Each wave OWNS its A-fragment:
// lane (m=lane&15, q=lane>>4) computes w(i0+m, kk+q*8+j) for j=0..7 in fp32,
// packs to bf16 in-register (v_perm), and feeds MFMA directly — no LDS, no
// __syncthreads in the K-loop. Block = 8 waves splitting K (wave w covers
// k in [w*1024, w*1024+1024), 32 k-steps of 32). Rowsum = 9th MFMA vs
// all-ones B. One barrier total for the cross-wave K reduction in LDS.
// exp trick: A_E = 4*A_I, so e_E = ((e_I)^2)^2 — 1 transcendental per w.

typedef float f32x4 __attribute__((ext_vector_type(4)));
typedef short s16x8 __attribute__((ext_vector_type(8)));
typedef unsigned int u32x4 __attribute__((ext_vector_type(4)));

#define NPTS 8192
#define DH 128
#define A_I (-0.5009357781f)  // -log2(e)/(2*1.2^2);  A_E = 4*A_I
#define GAIN_C 0.05f

// ---------- pre-pass: h [8192][128] f32 -> hT [128][8192] bf16 (d_ws) ----------
// Packed-word LDS tile, stride 17 words: write banks (17n+jj2)%32 — 17 coprime
// with 32 -> <=2-way (free). 256 blocks of 32 j-columns each.
__global__ __launch_bounds__(256) void h_transpose_bf16(
    const float* __restrict__ h, unsigned short* __restrict__ hT) {
  __shared__ __align__(16) unsigned int tileW[DH * 17];  // [n][jj2], jj2=0..15
  const int t = threadIdx.x;
  const int j0 = blockIdx.x * 32;
  const int n = t & 127;
  const int g = t >> 7;  // 0..1
#pragma unroll
  for (int p = 0; p < 8; ++p) {
    const int jj2 = g * 8 + p;  // packed pair index 0..15
    unsigned int a = __float_as_uint(h[(j0 + 2 * jj2) * DH + n]);
    unsigned int b = __float_as_uint(h[(j0 + 2 * jj2 + 1) * DH + n]);
    a = (a + 0x7fffu + ((a >> 16) & 1u)) >> 16;          // RNE low half
    b = (b + 0x7fffu + ((b >> 16) & 1u)) & 0xffff0000u;  // RNE high half
    tileW[n * 17 + jj2] = a | b;
  }
  __syncthreads();
  // write-out: 128 rows x 4 chunks(16B) = 512 chunk-writes, 2 iterations
#pragma unroll
  for (int k = 0; k < 2; ++k) {
    const int u = t + k * 256;
    const int rn = u >> 2;  // 0..127
    const int c = u & 3;    // 16B chunk
    u32x4 val;
#pragma unroll
    for (int i = 0; i < 4; ++i) val[i] = tileW[rn * 17 + c * 4 + i];
    *(u32x4*)(hT + rn * NPTS + j0 + c * 8) = val;
  }
}

// ---------- main fused kernel ----------
__global__ __launch_bounds__(512, 4) void lateral_ei_main(
    const float* __restrict__ z, const unsigned short* __restrict__ hT,
    float* __restrict__ out) {
  __shared__ __align__(16) float s_red[8 * 2048];  // [wave][m*128+c], 64 KB
  __shared__ float s_rs[8 * 16];                   // [wave][m] rowsum partials

  const int t = threadIdx.x;
  const int lane = t & 63;
  const int w = t >> 6;  // 0..7 — K-split index
  const int i0 = blockIdx.x * 16;
  const int nf = lane & 15;  // A-row m / B-col n
  const int q = lane >> 4;   // quad: A/B k-subrange q*8..q*8+8

  const int kk0 = w * 1024;

  // zi for this lane's A-row
  const float zix = z[(i0 + nf) * 2 + 0];
  const float ziy = z[(i0 + nf) * 2 + 1];

  // B-frag base: hT[(cf*16 + nf)*NPTS + kk0 + ks*32 + q*8]
  const unsigned short* hb = hT + nf * NPTS + kk0 + q * 8;
  // zj base for this lane's 8 k's
  const float* zj = z + (kk0 + q * 8) * 2;

  f32x4 acc[8];
#pragma unroll
  for (int cf = 0; cf < 8; ++cf) acc[cf] = (f32x4){0.f, 0.f, 0.f, 0.f};
  f32x4 acc9 = {0.f, 0.f, 0.f, 0.f};  // rowsum accumulator (ones-B MFMA)
  const s16x8 b_one = {16256, 16256, 16256, 16256,
                       16256, 16256, 16256, 16256};  // bf16 1.0 x8

  for (int ks = 0; ks < 32; ++ks) {
    const int kk = ks * 32;

    // B fragments: 8 x 16B global loads (L1/L2-resident hT)
    s16x8 b[8];
#pragma unroll
    for (int cf = 0; cf < 8; ++cf)
      b[cf] = *(const s16x8*)(hb + cf * (16 * NPTS) + kk);

    // zj: 8 (x,y) pairs = 4 x 16B (quad-uniform addresses, L1 broadcast)
    const f32x4 z01 = *(const f32x4*)(zj + kk * 2);
    const f32x4 z23 = *(const f32x4*)(zj + kk * 2 + 4);
    const f32x4 z45 = *(const f32x4*)(zj + kk * 2 + 8);
    const f32x4 z67 = *(const f32x4*)(zj + kk * 2 + 12);

    // 8 w's: ~9 VALU + 1 v_exp each, all chains independent
    float wv[8];
#pragma unroll
    for (int pr = 0; pr < 4; ++pr) {
      const f32x4 zp = (pr == 0) ? z01 : (pr == 1) ? z23 : (pr == 2) ? z45 : z67;
      const float dx0 = zix - zp[0], dy0 = ziy - zp[1];
      const float dx1 = zix - zp[2], dy1 = ziy - zp[3];
      const float d0 = dx0 * dx0 + dy0 * dy0;
      const float d1 = dx1 * dx1 + dy1 * dy1;
      const float ei0 = __builtin_amdgcn_exp2f(d0 * A_I);
      const float ei1 = __builtin_amdgcn_exp2f(d1 * A_I);
      const float sq0 = ei0 * ei0, sq1 = ei1 * ei1;
      const float ee0 = sq0 * sq0, ee1 = sq1 * sq1;  // e_E = e_I^4
      wv[pr * 2] = fmaf(0.8f, ee0, -ei0);
      wv[pr * 2 + 1] = fmaf(0.8f, ee1, -ei1);
    }

    // pack to bf16 A-fragment in-register: 4 x v_perm (truncate)
    union {
      unsigned int u[4];
      s16x8 v;
    } af;
#pragma unroll
    for (int pr = 0; pr < 4; ++pr)
      af.u[pr] = __builtin_amdgcn_perm(__float_as_uint(wv[pr * 2 + 1]),
                                       __float_as_uint(wv[pr * 2]), 0x07060302);
    const s16x8 a = af.v;

    // 9 MFMAs: 8 col-fragments + rowsum(ones)
#pragma unroll
    for (int cf = 0; cf < 8; ++cf)
      acc[cf] = __builtin_amdgcn_mfma_f32_16x16x32_bf16(a, b[cf], acc[cf], 0, 0, 0);
    acc9 = __builtin_amdgcn_mfma_f32_16x16x32_bf16(a, b_one, acc9, 0, 0, 0);
  }

  // ---- cross-wave K reduction (single barrier) ----
  // C/D layout: col = lane&15 (=nf), row = q*4 + r (verified m89/m91)
#pragma unroll
  for (int cf = 0; cf < 8; ++cf)
#pragma unroll
    for (int r = 0; r < 4; ++r)
      s_red[w * 2048 + (q * 4 + r) * 128 + cf * 16 + nf] = acc[cf][r];
  if (nf == 0) {  // acc9 identical across n — lanes 0,16,32,48 cover rows 0..15
#pragma unroll
    for (int r = 0; r < 4; ++r) s_rs[w * 16 + q * 4 + r] = acc9[r];
  }
  __syncthreads();

  // thread t -> output row m = t>>5, cols (t&31)*4 .. +4;  elem base = 4t
  const int m = t >> 5;
  float rsum = 0.f;
#pragma unroll
  for (int ww = 0; ww < 8; ++ww) rsum += s_rs[ww * 16 + m];  // broadcast reads
  f32x4 tot = {0.f, 0.f, 0.f, 0.f};
#pragma unroll
  for (int ww = 0; ww < 8; ++ww) tot += *(const f32x4*)&s_red[ww * 2048 + t * 4];
  const float sc = GAIN_C / (rsum + 1e-6f);
  *(f32x4*)(out + (i0 + m) * DH + (t & 31) * 4) = tot * sc;
}

extern "C" void kernel_launch(void* const* d_in, const int* in_sizes, int n_in,
                              void* d_out, int out_size, void* d_ws, size_t ws_size,
                              hipStream_t stream) {
  (void)in_sizes; (void)n_in; (void)out_size; (void)ws_size;
  const float* z = (const float*)d_in[0];
  const float* h = (const float*)d_in[1];
  float* out = (float*)d_out;
  unsigned short* hT = (unsigned short*)d_ws;  // 128*8192 bf16 = 2 MiB scratch

  h_transpose_bf16<<<NPTS / 32, 256, 0, stream>>>(h, hT);
  lateral_ei_main<<<NPTS / 16, 512, 0, stream>>>(z, hT, out);
}

// Round 4
// 94.408 us; speedup vs baseline: 2.1616x; 1.9997x over previous
//
#include <hip/hip_runtime.h>

// LateralEI: out = GAIN * rownorm(K) @ h, K = 0.8*exp(-d2/0.72) - exp(-d2/2.88)
// z: [8192][2] f32, h: [8192][128] f32, out: [8192][128] f32
//
// R4: fix the vmem request-rate bottleneck (R2/R3 ~140us, VALUBusy 16%).
//  - hTf: h pre-transposed to bf16 in FRAGMENT-MAJOR order: fragment
//    (k5, cf) = 1KB contiguous block, lane-ordered — B-loads fully coalesced.
//  - One wave = 32 rows (2 A-frags) x K-slice 1024: B traffic halves, each
//    block streams hTf (2 MiB, L2-resident) exactly once. 18 MFMA/iter.
//  - w via fma-form: u = A_I*d2 = cA + aZj2[k] + cX*zjx + cY*zjy (tables),
//    e_E = e_I^4 (A_E = 4*A_I): 7 VALU + 1 exp per w.
//  - No barriers in K-loop; manual double-buffer on B; single barrier for
//    the cross-wave K reduction.

typedef float f32x4 __attribute__((ext_vector_type(4)));
typedef short s16x8 __attribute__((ext_vector_type(8)));
typedef unsigned int u32x4 __attribute__((ext_vector_type(4)));

#define NPTS 8192
#define DH 128
#define A_I (-0.5009357781f)  // -log2(e)/(2*1.2^2); A_E = 4*A_I
#define GAIN_C 0.05f

#define RED_STRIDE 132                    // 32 rows * 132 words per wk slice
#define RED_WK (32 * RED_STRIDE)          // 4224 words

// ---------- pre-pass A: aZj2[k] = A_I * |z_k|^2 ----------
__global__ __launch_bounds__(256) void z_norm_pre(
    const float* __restrict__ z, float* __restrict__ aZj2) {
  const int g = blockIdx.x * 256 + threadIdx.x;
  const float x = z[g * 2 + 0];
  const float y = z[g * 2 + 1];
  aZj2[g] = A_I * (x * x + y * y);
}

// ---------- pre-pass B: h [8192][128] f32 -> hTf fragment-major bf16 ----------
// Fragment (k5=k>>5, cf): 512 halfwords at hTf[(k5*8+cf)*512], chunk for lane
// (q=lane>>4, nf=lane&15) at +lane*8: h[k5*32+q*8+j][cf*16+nf], j=0..7.
__global__ __launch_bounds__(256) void h_to_hTf(
    const float* __restrict__ h, unsigned short* __restrict__ hTf) {
  __shared__ unsigned int tileW[DH * 17];  // [n][kp], kp = k-pair 0..15
  const int t = threadIdx.x;
  const int k5 = blockIdx.x;
  const int n = t & 127;
  const int g = t >> 7;  // 0..1
#pragma unroll
  for (int p = 0; p < 8; ++p) {
    const int kp = g * 8 + p;
    unsigned int a = __float_as_uint(h[(k5 * 32 + 2 * kp) * DH + n]);
    unsigned int b = __float_as_uint(h[(k5 * 32 + 2 * kp + 1) * DH + n]);
    a = (a + 0x7fffu + ((a >> 16) & 1u)) >> 16;          // RNE low half
    b = (b + 0x7fffu + ((b >> 16) & 1u)) & 0xffff0000u;  // RNE high half
    tileW[n * 17 + kp] = a | b;
  }
  __syncthreads();
  // 512 16B-chunks: u = cf*64 + lane
#pragma unroll
  for (int it = 0; it < 2; ++it) {
    const int u = t + it * 256;
    const int cf = u >> 6;
    const int lane = u & 63;
    const int nf = lane & 15;
    const int q = lane >> 4;
    const int n2 = cf * 16 + nf;
    u32x4 val;
#pragma unroll
    for (int i = 0; i < 4; ++i) val[i] = tileW[n2 * 17 + q * 4 + i];
    *(u32x4*)(hTf + k5 * 4096 + u * 8) = val;
  }
}

// ---------- main fused kernel ----------
__global__ __launch_bounds__(512, 2) void lateral_ei_main(
    const float* __restrict__ z, const unsigned short* __restrict__ hTf,
    const float* __restrict__ aZj2, float* __restrict__ out) {
  __shared__ float s_red[8 * RED_WK];  // [wk][row 0..31][col 0..127], ~132KB
  __shared__ float s_rs[8 * 32];       // [wk][row] rowsum partials

  const int t = threadIdx.x;
  const int lane = t & 63;
  const int wk = t >> 6;  // K-split 0..7
  const int i0 = blockIdx.x * 32;
  const int nf = lane & 15;
  const int q = lane >> 4;
  const int kk0 = wk * 1024;

  // lane constants for the two row-groups (rows i0+nf, i0+16+nf)
  const float zix0 = z[(i0 + nf) * 2 + 0], ziy0 = z[(i0 + nf) * 2 + 1];
  const float zix1 = z[(i0 + 16 + nf) * 2 + 0], ziy1 = z[(i0 + 16 + nf) * 2 + 1];
  const float cA0 = A_I * (zix0 * zix0 + ziy0 * ziy0);
  const float cA1 = A_I * (zix1 * zix1 + ziy1 * ziy1);
  const float cX0 = -2.f * A_I * zix0, cY0 = -2.f * A_I * ziy0;
  const float cX1 = -2.f * A_I * zix1, cY1 = -2.f * A_I * ziy1;

  // pointers for this lane
  const unsigned short* bp = hTf + (wk * 32) * 4096 + lane * 8;  // +ks*4096+cf*512
  const float* zj = z + (kk0 + q * 8) * 2;                       // +ks*64
  const float* ap = aZj2 + kk0 + q * 8;                          // +ks*32

  f32x4 acc0[8], acc1[8];
#pragma unroll
  for (int cf = 0; cf < 8; ++cf) {
    acc0[cf] = (f32x4){0.f, 0.f, 0.f, 0.f};
    acc1[cf] = (f32x4){0.f, 0.f, 0.f, 0.f};
  }
  f32x4 rs0 = {0.f, 0.f, 0.f, 0.f}, rs1 = {0.f, 0.f, 0.f, 0.f};
  const s16x8 b_one = {16256, 16256, 16256, 16256,
                       16256, 16256, 16256, 16256};  // bf16 1.0

  // double-buffered B fragments
  s16x8 bb[2][8];
#pragma unroll
  for (int cf = 0; cf < 8; ++cf) bb[0][cf] = *(const s16x8*)(bp + cf * 512);

#pragma unroll 2
  for (int ks = 0; ks < 32; ++ks) {
    const int cur = ks & 1, nxt = cur ^ 1;
    if (ks + 1 < 32) {
      const unsigned short* bpn = bp + (ks + 1) * 4096;
#pragma unroll
      for (int cf = 0; cf < 8; ++cf) bb[nxt][cf] = *(const s16x8*)(bpn + cf * 512);
    }

    // zj pairs + aZj2 for this iter's 8 k's (quad-uniform, L1/L2-hot)
    const f32x4 zA = *(const f32x4*)(zj + ks * 64 + 0);   // k0,k1
    const f32x4 zB = *(const f32x4*)(zj + ks * 64 + 4);   // k2,k3
    const f32x4 zC = *(const f32x4*)(zj + ks * 64 + 8);   // k4,k5
    const f32x4 zD = *(const f32x4*)(zj + ks * 64 + 12);  // k6,k7
    const f32x4 aA = *(const f32x4*)(ap + ks * 32);       // az k0..k3
    const f32x4 aB = *(const f32x4*)(ap + ks * 32 + 4);   // az k4..k7

    float wv0[8], wv1[8];
#pragma unroll
    for (int j = 0; j < 8; ++j) {
      const f32x4 zp = (j < 2) ? zA : (j < 4) ? zB : (j < 6) ? zC : zD;
      const float zjx = zp[(j & 1) * 2], zjy = zp[(j & 1) * 2 + 1];
      const float az = (j < 4) ? aA[j] : aB[j - 4];
      const float u0 = fmaf(cX0, zjx, fmaf(cY0, zjy, cA0 + az));
      const float u1 = fmaf(cX1, zjx, fmaf(cY1, zjy, cA1 + az));
      const float ei0 = __builtin_amdgcn_exp2f(u0);
      const float ei1 = __builtin_amdgcn_exp2f(u1);
      const float s0 = ei0 * ei0, s1 = ei1 * ei1;
      const float e0 = s0 * s0, e1 = s1 * s1;  // e_E = e_I^4
      wv0[j] = fmaf(0.8f, e0, -ei0);
      wv1[j] = fmaf(0.8f, e1, -ei1);
    }

    // pack to bf16 A-fragments (truncate; matches R2/R3-verified math)
    union { unsigned int u[4]; s16x8 v; } af0, af1;
#pragma unroll
    for (int p = 0; p < 4; ++p) {
      af0.u[p] = __builtin_amdgcn_perm(__float_as_uint(wv0[2 * p + 1]),
                                       __float_as_uint(wv0[2 * p]), 0x07060302);
      af1.u[p] = __builtin_amdgcn_perm(__float_as_uint(wv1[2 * p + 1]),
                                       __float_as_uint(wv1[2 * p]), 0x07060302);
    }
    const s16x8 a0 = af0.v, a1 = af1.v;

#pragma unroll
    for (int cf = 0; cf < 8; ++cf) {
      acc0[cf] = __builtin_amdgcn_mfma_f32_16x16x32_bf16(a0, bb[cur][cf], acc0[cf], 0, 0, 0);
      acc1[cf] = __builtin_amdgcn_mfma_f32_16x16x32_bf16(a1, bb[cur][cf], acc1[cf], 0, 0, 0);
    }
    rs0 = __builtin_amdgcn_mfma_f32_16x16x32_bf16(a0, b_one, rs0, 0, 0, 0);
    rs1 = __builtin_amdgcn_mfma_f32_16x16x32_bf16(a1, b_one, rs1, 0, 0, 0);
  }

  // ---- cross-wave K reduction (single barrier) ----
  // C/D layout: col = lane&15 (=nf), row = q*4 + r
#pragma unroll
  for (int cf = 0; cf < 8; ++cf)
#pragma unroll
    for (int r = 0; r < 4; ++r) {
      s_red[wk * RED_WK + (q * 4 + r) * RED_STRIDE + cf * 16 + nf] = acc0[cf][r];
      s_red[wk * RED_WK + (16 + q * 4 + r) * RED_STRIDE + cf * 16 + nf] = acc1[cf][r];
    }
  if (nf == 0) {
#pragma unroll
    for (int r = 0; r < 4; ++r) {
      s_rs[wk * 32 + q * 4 + r] = rs0[r];
      s_rs[wk * 32 + 16 + q * 4 + r] = rs1[r];
    }
  }
  __syncthreads();

  // thread t -> row m = t>>4 (0..31), cols (t&15)*8 .. +8
  const int m = t >> 4;
  const int c0 = (t & 15) * 8;
  float rsum = 0.f;
#pragma unroll
  for (int w8 = 0; w8 < 8; ++w8) rsum += s_rs[w8 * 32 + m];
  f32x4 lo = {0.f, 0.f, 0.f, 0.f}, hi = {0.f, 0.f, 0.f, 0.f};
#pragma unroll
  for (int w8 = 0; w8 < 8; ++w8) {
    const float* p = &s_red[w8 * RED_WK + m * RED_STRIDE + c0];
    lo += *(const f32x4*)p;
    hi += *(const f32x4*)(p + 4);
  }
  const float sc = GAIN_C / (rsum + 1e-6f);
  *(f32x4*)(out + (i0 + m) * DH + c0) = lo * sc;
  *(f32x4*)(out + (i0 + m) * DH + c0 + 4) = hi * sc;
}

extern "C" void kernel_launch(void* const* d_in, const int* in_sizes, int n_in,
                              void* d_out, int out_size, void* d_ws, size_t ws_size,
                              hipStream_t stream) {
  (void)in_sizes; (void)n_in; (void)out_size; (void)ws_size;
  const float* z = (const float*)d_in[0];
  const float* h = (const float*)d_in[1];
  float* out = (float*)d_out;
  unsigned short* hTf = (unsigned short*)d_ws;                    // 2 MiB
  float* aZj2 = (float*)((char*)d_ws + 2 * 1024 * 1024);          // 32 KiB

  z_norm_pre<<<NPTS / 256, 256, 0, stream>>>(z, aZj2);
  h_to_hTf<<<NPTS / 32, 256, 0, stream>>>(h, hTf);
  lateral_ei_main<<<NPTS / 32, 512, 0, stream>>>(z, hTf, aZj2, out);
}